// Round 7
// baseline (10629.002 us; speedup 1.0000x reference)
//
#include <hip/hip_runtime.h>
#include <hip/hip_fp16.h>
#include <cstdint>

// LSTMNet: embed(128->512) -> 3x LSTM(512) -> decode last step.
// B=256, T=256. f16 MFMA (16x16x32), fp32 accum, fp32 cell state.
//
// Persistent k_rec, 256 blocks (coop), static g=blockIdx&7 (32 batch rows),
// hb=blockIdx>>3 (16 hidden units). Memory model: agent-scope relaxed atomics
// ONLY (proven R3/R5). NEW: self-validating tagged h-exchange -
//   producer stores each h as one u32 word: (epoch+1)<<16 | f16bits, into a
//   2-slot ring tagh[slot=epoch&1][256][512]. Tag+data land atomically ->
//   NO producer vmcnt drain, NO flag, NO release barrier on the critical path.
//   Consumers poll the words directly (check high16 == want) and unpack
//   (hi<<16)|(lo&0xffff) into MFMA A-frags. Tags monotone 1..768; zero-init
//   each launch; 0xAAAA poison can't match; replay-stale tags carry identical
//   deterministic values (same inputs -> same h) so even they are benign.
// Once per layer (t=255): vmcnt(0) before the final tags, ordering the plain
// f16 X-copy (next layer's input) behind the layer-end tags.
// Pl partials ping-pong by t&1 -> ONE __syncthreads per step.
// All spins guarded (trip -> never wait again; wrong answer, no wedge).

#define TSEQ 256
#define NBAT 256
#define DIN  128
#define HID  512
#define NL   3

typedef _Float16 half_t;
typedef __attribute__((ext_vector_type(8))) _Float16 half8;
typedef __attribute__((ext_vector_type(4))) _Float16 half4v;
typedef __attribute__((ext_vector_type(4))) float f32x4;

__device__ __forceinline__ float sigmoidf_(float x) {
    return 1.f / (1.f + __expf(-x));
}
__device__ __forceinline__ float tanhf_(float x) {
    float xc = fminf(fmaxf(x, -15.f), 15.f);
    float e = __expf(2.f * xc);
    return (e - 1.f) / (e + 1.f);
}

// agent-scope (IF-coherent) 16B load
__device__ __forceinline__ half8 ld_cg16(const half_t* p) {
    union { unsigned long long u[2]; half8 v; } r;
    r.u[0] = __hip_atomic_load((const unsigned long long*)p,
                               __ATOMIC_RELAXED, __HIP_MEMORY_SCOPE_AGENT);
    r.u[1] = __hip_atomic_load((const unsigned long long*)p + 1,
                               __ATOMIC_RELAXED, __HIP_MEMORY_SCOPE_AGENT);
    return r.v;
}
// agent-scope 2B store of one h value (plain X-copy for next layer)
__device__ __forceinline__ void st_cg2(half_t* p, float v) {
    half_t h = (half_t)v;
    unsigned short b = __builtin_bit_cast(unsigned short, h);
    __hip_atomic_store((unsigned short*)p, b,
                       __ATOMIC_RELAXED, __HIP_MEMORY_SCOPE_AGENT);
}

// ---------------- embed: out[t][b][j] = f16( x[b][t][:] . W[j][:] + bias[j] )
__global__ __launch_bounds__(256) void k_embed(const float* __restrict__ x,
                                               const float* __restrict__ W,
                                               const float* __restrict__ bias,
                                               half_t* __restrict__ out) {
    extern __shared__ char smem[];
    half_t* Xs = (half_t*)smem;            // [64][128] swizzled
    half_t* Ws = (half_t*)(smem + 16384);  // [512][128] swizzled
    const int tid = threadIdx.x;
    const int bk = blockIdx.x;
    const int t = bk >> 2, b0 = (bk & 3) << 6;

    #pragma unroll
    for (int it = 0; it < 8; ++it) {
        int idx = tid + (it << 8);
        int r = idx >> 5, k = (idx & 31) << 2;
        float4 v = *(const float4*)(x + ((size_t)(b0 + r) * TSEQ + t) * DIN + k);
        half4v hv = {(half_t)v.x, (half_t)v.y, (half_t)v.z, (half_t)v.w};
        int byte = r * 256 + ((k * 2) ^ ((r & 7) << 4));
        *(half4v*)((char*)Xs + byte) = hv;
    }
    #pragma unroll 4
    for (int it = 0; it < 64; ++it) {
        int idx = tid + (it << 8);
        int r = idx >> 5, k = (idx & 31) << 2;
        float4 v = *(const float4*)(W + (size_t)r * DIN + k);
        half4v hv = {(half_t)v.x, (half_t)v.y, (half_t)v.z, (half_t)v.w};
        int byte = r * 256 + ((k * 2) ^ ((r & 7) << 4));
        *(half4v*)((char*)Ws + byte) = hv;
    }
    __syncthreads();

    const int lane = tid & 63, wv = tid >> 6;
    f32x4 acc[4][8];
    #pragma unroll
    for (int m = 0; m < 4; ++m)
        #pragma unroll
        for (int n = 0; n < 8; ++n) acc[m][n] = (f32x4){0.f, 0.f, 0.f, 0.f};

    #pragma unroll
    for (int kit = 0; kit < 4; ++kit) {
        int kk = (kit << 5) + ((lane >> 4) << 3);
        half8 a[4];
        #pragma unroll
        for (int m = 0; m < 4; ++m) {
            int r = (m << 4) + (lane & 15);
            int byte = r * 256 + ((kk * 2) ^ ((r & 7) << 4));
            a[m] = *(half8*)((char*)Xs + byte);
        }
        #pragma unroll
        for (int n = 0; n < 8; ++n) {
            int r = (wv << 7) + (n << 4) + (lane & 15);
            int byte = r * 256 + ((kk * 2) ^ ((r & 7) << 4));
            half8 b = *(half8*)((char*)Ws + byte);
            #pragma unroll
            for (int m = 0; m < 4; ++m)
                acc[m][n] = __builtin_amdgcn_mfma_f32_16x16x32_f16(a[m], b, acc[m][n], 0, 0, 0);
        }
    }
    __syncthreads();
    half_t* Os = (half_t*)smem;
    #pragma unroll
    for (int n = 0; n < 8; ++n) {
        int j = (wv << 7) + (n << 4) + (lane & 15);
        float bj = bias[j];
        #pragma unroll
        for (int m = 0; m < 4; ++m)
            #pragma unroll
            for (int r = 0; r < 4; ++r) {
                int mr = (m << 4) + ((lane >> 4) << 2) + r;
                Os[mr * 512 + j] = (half_t)(acc[m][n][r] + bj);
            }
    }
    __syncthreads();
    #pragma unroll
    for (int it = 0; it < 16; ++it) {
        int idx = tid + (it << 8);
        int r = idx >> 6, c = (idx & 63) << 3;
        half8 v = *(half8*)(Os + r * 512 + c);
        *(half8*)(out + ((size_t)t * NBAT + (b0 + r)) * HID + c) = v;
    }
}

// ---------------- persistent recurrent kernel (all 3 layers, 256 steps each)
__global__ __launch_bounds__(256, 1) void k_rec(const float* __restrict__ w_ih,
                                                const float* __restrict__ w_hh,
                                                const float* __restrict__ b_ih,
                                                const float* __restrict__ b_hh,
                                                half_t* __restrict__ bufA,
                                                half_t* __restrict__ bufB,
                                                uint32_t* __restrict__ tagh) {
    extern __shared__ char smem[];
    float* Pl = (float*)smem;                 // 2 x [128][64] f32 partials, XOR-swz

    const int tid = threadIdx.x;
    const int lane = tid & 63, wv = tid >> 6;
    const int g = blockIdx.x & 7;             // batch group (static)
    const int hb = blockIdx.x >> 3;           // hidden part 0..31
    const int b0 = g << 5;
    const int j0 = hb << 4;

    const int rr = tid >> 4;                  // reduce row 0..15
    const int jj = tid & 15;                  // reduce unit 0..15
    const bool hpart = (wv >= 2);
    const int kc = (wv & 1) << 8;             // K-chunk within source matrix
    const float* wsrc = hpart ? w_hh : w_ih;
    bool dead = false;

    float c0 = 0.f, c1 = 0.f;
    float bias[4];
    half8 Bf[8][4];                           // weight B-fragments (128 VGPR)
    half8 xa[8], xb[8];                       // X prefetch regs (X-waves)
    half8 ha[8], hc[8];                       // h A-frags (h-waves, from tags)

    for (int l = 0; l < NL; ++l) {
        const half_t* inb = (l & 1) ? bufB : bufA;
        half_t* outb = (l & 1) ? bufA : bufB;

        // ---- per-layer: weight fragments fp32 -> f16 into VGPRs
        #pragma unroll
        for (int kit = 0; kit < 8; ++kit)
            #pragma unroll
            for (int n = 0; n < 4; ++n) {
                int grow = l * 2048 + n * 512 + j0 + (lane & 15);
                int col = kc + (kit << 5) + ((lane >> 4) << 3);
                const float* p = wsrc + (size_t)grow * HID + col;
                float4 u0 = *(const float4*)p;
                float4 u1 = *(const float4*)(p + 4);
                Bf[kit][n] = (half8){(half_t)u0.x, (half_t)u0.y, (half_t)u0.z, (half_t)u0.w,
                                     (half_t)u1.x, (half_t)u1.y, (half_t)u1.z, (half_t)u1.w};
            }
        #pragma unroll
        for (int gt = 0; gt < 4; ++gt)
            bias[gt] = b_ih[(size_t)l * 2048 + gt * HID + j0 + jj] +
                       b_hh[(size_t)l * 2048 + gt * HID + j0 + jj];
        c0 = c1 = 0.f;

        for (int t = 0; t < TSEQ; ++t) {
            const int e = (l << 8) + t;       // epoch 0..767

            // ---- h-waves: poll tagged h(t-1) words (tag high16 == e), unpack
            if (hpart && e > 0 && !dead) {
                const uint32_t wanthi = (uint32_t)e << 16;
                const uint32_t* tb = tagh + (size_t)((e - 1) & 1) * (NBAT * HID)
                                     + (size_t)(b0 + (lane & 15)) * HID
                                     + kc + ((lane >> 4) << 3);
                const unsigned long long* t0 = (const unsigned long long*)tb;
                const unsigned long long* t1 = (const unsigned long long*)(tb + 16 * HID);
                int guard = 0;
                bool good = false;
                while (!__all(good)) {
                    uint32_t bad = 0;
                    #pragma unroll
                    for (int kit = 0; kit < 8; ++kit) {
                        unsigned long long q[4], r[4];
                        #pragma unroll
                        for (int j = 0; j < 4; ++j) {
                            q[j] = __hip_atomic_load(t0 + kit * 16 + j,
                                                     __ATOMIC_RELAXED, __HIP_MEMORY_SCOPE_AGENT);
                            r[j] = __hip_atomic_load(t1 + kit * 16 + j,
                                                     __ATOMIC_RELAXED, __HIP_MEMORY_SCOPE_AGENT);
                        }
                        union { uint32_t u[4]; half8 v; } pa, pb;
                        #pragma unroll
                        for (int j = 0; j < 4; ++j) {
                            uint32_t lo = (uint32_t)q[j], hi = (uint32_t)(q[j] >> 32);
                            bad |= (lo ^ wanthi) & 0xFFFF0000u;
                            bad |= (hi ^ wanthi) & 0xFFFF0000u;
                            pa.u[j] = (hi << 16) | (lo & 0xFFFFu);
                            uint32_t lo2 = (uint32_t)r[j], hi2 = (uint32_t)(r[j] >> 32);
                            bad |= (lo2 ^ wanthi) & 0xFFFF0000u;
                            bad |= (hi2 ^ wanthi) & 0xFFFF0000u;
                            pb.u[j] = (hi2 << 16) | (lo2 & 0xFFFFu);
                        }
                        ha[kit] = pa.v;
                        hc[kit] = pb.v;
                    }
                    good = (bad == 0);
                    if (!__all(good)) {
                        if (++guard > (1 << 17)) { dead = true; break; }
                    }
                }
            }
            // layer-transition gate: X-waves may not touch inb until the
            // h-wave poll has verified the previous layer's final tags.
            if (t == 0) __syncthreads();

            f32x4 acc[2][4];
            #pragma unroll
            for (int m = 0; m < 2; ++m)
                #pragma unroll
                for (int n = 0; n < 4; ++n) acc[m][n] = (f32x4){0.f, 0.f, 0.f, 0.f};

            if (!hpart) {
                if (t == 0) {
                    const half_t* ar = inb + ((size_t)b0 + (lane & 15)) * HID
                                       + kc + ((lane >> 4) << 3);
                    #pragma unroll
                    for (int kit = 0; kit < 8; ++kit) {
                        xa[kit] = ld_cg16(ar + (kit << 5));
                        xb[kit] = ld_cg16(ar + (size_t)16 * HID + (kit << 5));
                    }
                }
                #pragma unroll
                for (int kit = 0; kit < 8; ++kit)
                    #pragma unroll
                    for (int n = 0; n < 4; ++n) {
                        acc[0][n] = __builtin_amdgcn_mfma_f32_16x16x32_f16(xa[kit], Bf[kit][n], acc[0][n], 0, 0, 0);
                        acc[1][n] = __builtin_amdgcn_mfma_f32_16x16x32_f16(xb[kit], Bf[kit][n], acc[1][n], 0, 0, 0);
                    }
                if (t + 1 < TSEQ) {  // prefetch X(t+1); hides under reduce
                    const half_t* ar = inb + ((size_t)(t + 1) * NBAT + b0 + (lane & 15)) * HID
                                       + kc + ((lane >> 4) << 3);
                    #pragma unroll
                    for (int kit = 0; kit < 8; ++kit) {
                        xa[kit] = ld_cg16(ar + (kit << 5));
                        xb[kit] = ld_cg16(ar + (size_t)16 * HID + (kit << 5));
                    }
                }
            } else if (t > 0) {
                #pragma unroll
                for (int kit = 0; kit < 8; ++kit)
                    #pragma unroll
                    for (int n = 0; n < 4; ++n) {
                        acc[0][n] = __builtin_amdgcn_mfma_f32_16x16x32_f16(ha[kit], Bf[kit][n], acc[0][n], 0, 0, 0);
                        acc[1][n] = __builtin_amdgcn_mfma_f32_16x16x32_f16(hc[kit], Bf[kit][n], acc[1][n], 0, 0, 0);
                    }
            }

            // ---- partials into ping-pong slot (2-way swz = free)
            float* Plc = Pl + ((t & 1) << 13);
            #pragma unroll
            for (int m = 0; m < 2; ++m)
                #pragma unroll
                for (int n = 0; n < 4; ++n)
                    #pragma unroll
                    for (int r = 0; r < 4; ++r) {
                        int prow = (wv << 5) + (m << 4) + ((lane >> 4) << 2) + r;
                        int cidx = (n << 4) + (lane & 15);
                        Plc[prow * 64 + (cidx ^ ((((prow >> 2) ^ prow) & 1) << 4))] = acc[m][n][r];
                    }
            __syncthreads();   // the ONE barrier per step

            // ---- reduce + gates: thread (rr,jj) owns batch rows rr and rr+16
            float sv0[4], sv1[4];
            #pragma unroll
            for (int gt = 0; gt < 4; ++gt) {
                float s0 = bias[gt], s1 = bias[gt];
                int cidx = (gt << 4) + jj;
                #pragma unroll
                for (int w2 = 0; w2 < 4; ++w2) {
                    int r0 = (w2 << 5) + rr;
                    int r1 = (w2 << 5) + 16 + rr;
                    s0 += Plc[r0 * 64 + (cidx ^ ((((r0 >> 2) ^ r0) & 1) << 4))];
                    s1 += Plc[r1 * 64 + (cidx ^ ((((r1 >> 2) ^ r1) & 1) << 4))];
                }
                sv0[gt] = s0; sv1[gt] = s1;
            }
            float h0v, h1v;
            {
                float ig = sigmoidf_(sv0[0]), fg = sigmoidf_(sv0[1]);
                float gg = tanhf_(sv0[2]), og = sigmoidf_(sv0[3]);
                c0 = fg * c0 + ig * gg;
                h0v = og * tanhf_(c0);
            }
            {
                float ig = sigmoidf_(sv1[0]), fg = sigmoidf_(sv1[1]);
                float gg = tanhf_(sv1[2]), og = sigmoidf_(sv1[3]);
                c1 = fg * c1 + ig * gg;
                h1v = og * tanhf_(c1);
            }
            // plain f16 copy (next layer's X / decoder input)
            st_cg2(outb + ((size_t)t * NBAT + b0 + rr) * HID + j0 + jj, h0v);
            st_cg2(outb + ((size_t)t * NBAT + b0 + 16 + rr) * HID + j0 + jj, h1v);
            // layer end: order ALL this layer's plain copies before final tags
            if (t == TSEQ - 1) {
                asm volatile("s_waitcnt vmcnt(0)" ::: "memory");
                __builtin_amdgcn_sched_barrier(0);
            }
            // tagged words: (e+1)<<16 | f16 bits  (atomic per-word tag+data)
            {
                uint32_t tagv = (uint32_t)(e + 1) << 16;
                uint32_t w0 = tagv | (uint32_t)__builtin_bit_cast(unsigned short, (half_t)h0v);
                uint32_t w1 = tagv | (uint32_t)__builtin_bit_cast(unsigned short, (half_t)h1v);
                uint32_t* tslot = tagh + (size_t)(e & 1) * (NBAT * HID);
                __hip_atomic_store(tslot + (size_t)(b0 + rr) * HID + j0 + jj, w0,
                                   __ATOMIC_RELAXED, __HIP_MEMORY_SCOPE_AGENT);
                __hip_atomic_store(tslot + (size_t)(b0 + 16 + rr) * HID + j0 + jj, w1,
                                   __ATOMIC_RELAXED, __HIP_MEMORY_SCOPE_AGENT);
            }
            // no drain, no flag, no release barrier -> straight into next step
        }
    }
}

// ---------------- decoder: out[b] = act[T-1][b][:] . dec_W + dec_b
__global__ __launch_bounds__(256) void k_dec(const half_t* __restrict__ act,
                                             const float* __restrict__ dW,
                                             const float* __restrict__ db,
                                             float* __restrict__ out) {
    int tid = threadIdx.x;
    int bl = tid >> 3, part = tid & 7;
    int b = (blockIdx.x << 5) + bl;
    const half_t* row = act + ((size_t)(TSEQ - 1) * NBAT + b) * HID + (part << 6);
    float s = 0.f;
    #pragma unroll
    for (int i = 0; i < 8; ++i) {
        half8 v = ld_cg16(row + (i << 3));
        const float* wp = dW + (part << 6) + (i << 3);
        #pragma unroll
        for (int u = 0; u < 8; ++u) s += (float)v[u] * wp[u];
    }
    #pragma unroll
    for (int off = 1; off < 8; off <<= 1) s += __shfl_xor(s, off, 64);
    if (part == 0) out[b] = s + db[0];
}

extern "C" void kernel_launch(void* const* d_in, const int* in_sizes, int n_in,
                              void* d_out, int out_size, void* d_ws, size_t ws_size,
                              hipStream_t stream) {
    const float* x = (const float*)d_in[0];
    const float* eW = (const float*)d_in[1];
    const float* eb = (const float*)d_in[2];
    const float* wih = (const float*)d_in[3];
    const float* whh = (const float*)d_in[4];
    const float* bih = (const float*)d_in[5];
    const float* bhh = (const float*)d_in[6];
    const float* dW = (const float*)d_in[7];
    const float* db = (const float*)d_in[8];
    float* out = (float*)d_out;

    const size_t BUF = (size_t)TSEQ * NBAT * HID * sizeof(half_t);   // 64 MB
    const size_t TAG = (size_t)2 * NBAT * HID * sizeof(uint32_t);    // 1 MB
    if (ws_size < 2 * BUF + TAG + 4096) return;  // insufficient workspace

    char* ws = (char*)d_ws;
    half_t* bufA = (half_t*)ws;
    half_t* bufB = (half_t*)(ws + BUF);
    uint32_t* tagh = (uint32_t*)(ws + 2 * BUF);

    // tags must start invalid (0). Runs every launch -> replay-deterministic.
    hipMemsetAsync(tagh, 0, TAG, stream);

    (void)hipFuncSetAttribute((const void*)k_embed,
                              hipFuncAttributeMaxDynamicSharedMemorySize, 147456);
    (void)hipFuncSetAttribute((const void*)k_rec,
                              hipFuncAttributeMaxDynamicSharedMemorySize, 98304);

    k_embed<<<1024, 256, 147456, stream>>>(x, eW, eb, bufA);

    // 96KB dynamic LDS -> 1 block/CU; cooperative -> co-resident.
    void* args[] = { (void*)&wih, (void*)&whh, (void*)&bih, (void*)&bhh,
                     (void*)&bufA, (void*)&bufB, (void*)&tagh };
    hipError_t ce = hipLaunchCooperativeKernel((const void*)k_rec, dim3(256), dim3(256),
                                               args, 98304, stream);
    if (ce != hipSuccess) {
        k_rec<<<256, 256, 98304, stream>>>(wih, whh, bih, bhh, bufA, bufB, tagh);
    }

    k_dec<<<8, 256, 0, stream>>>(bufB, dW, db, out);
}

// Round 8
// 3476.199 us; speedup vs baseline: 3.0577x; 3.0577x over previous
//
#include <hip/hip_runtime.h>
#include <hip/hip_fp16.h>
#include <cstdint>

// LSTMNet: embed(128->512) -> 3x LSTM(512) -> decode last step.
// B=256, T=256. f16 MFMA (16x16x32), fp32 accum, fp32 cell state.
//
// Persistent k_rec, 256 blocks (coop), static g=blockIdx&7 (32 batch rows),
// hb=blockIdx>>3 (16 hidden units). Sync = R5's proven flag scheme:
// per-step h stores (agent scope) -> vmcnt(0) drain -> barrier -> flag store;
// h-waves poll 32 group flags (agent scope) then load h(t-1).
// R8 delta: X loads for layers 0,1 are PLAIN CACHED loads - X data is
// write-once-per-address and replay-deterministic, so any stale cached line
// holds the identical value (embed/layer-(l-1) output never changes). Layer 2
// keeps agent-scope X (its input buffer bufA was plain-cached during layer 0
// with different values). h loads: issue-only asm sc0 sc1 x32 + single
// vmcnt(0) + sched_barrier(0) (rule #18) -> guaranteed batched issue.
// All spins guarded (trip -> never wait again; no wedge).

#define TSEQ 256
#define NBAT 256
#define DIN  128
#define HID  512
#define NL   3

typedef _Float16 half_t;
typedef __attribute__((ext_vector_type(8))) _Float16 half8;
typedef __attribute__((ext_vector_type(4))) _Float16 half4v;
typedef __attribute__((ext_vector_type(4))) float f32x4;

__device__ __forceinline__ float sigmoidf_(float x) {
    return 1.f / (1.f + __expf(-x));
}
__device__ __forceinline__ float tanhf_(float x) {
    float xc = fminf(fmaxf(x, -15.f), 15.f);
    float e = __expf(2.f * xc);
    return (e - 1.f) / (e + 1.f);
}

// agent-scope (IF-coherent) 16B load, compiler-managed wait (k_dec only)
__device__ __forceinline__ half8 ld_cg16(const half_t* p) {
    union { unsigned long long u[2]; half8 v; } r;
    r.u[0] = __hip_atomic_load((const unsigned long long*)p,
                               __ATOMIC_RELAXED, __HIP_MEMORY_SCOPE_AGENT);
    r.u[1] = __hip_atomic_load((const unsigned long long*)p + 1,
                               __ATOMIC_RELAXED, __HIP_MEMORY_SCOPE_AGENT);
    return r.v;
}
// agent-scope 16B load, ISSUE ONLY (sc0 sc1 = bypass L1+L2, read at MALL).
// Pair with wait_vm0() before any use of dst.
__device__ __forceinline__ void ld16_agent(half8& dst, const half_t* p) {
    asm volatile("global_load_dwordx4 %0, %1, off sc0 sc1" : "=v"(dst) : "v"(p));
}
// drain all vmem; sched_barrier stops MFMA hoisting above it (rule #18)
__device__ __forceinline__ void wait_vm0() {
    asm volatile("s_waitcnt vmcnt(0)" ::: "memory");
    __builtin_amdgcn_sched_barrier(0);
}
// agent-scope 2B store of one h value
__device__ __forceinline__ void st_cg2(half_t* p, float v) {
    half_t h = (half_t)v;
    unsigned short b = __builtin_bit_cast(unsigned short, h);
    __hip_atomic_store((unsigned short*)p, b,
                       __ATOMIC_RELAXED, __HIP_MEMORY_SCOPE_AGENT);
}

// ---------------- embed: out[t][b][j] = f16( x[b][t][:] . W[j][:] + bias[j] )
__global__ __launch_bounds__(256) void k_embed(const float* __restrict__ x,
                                               const float* __restrict__ W,
                                               const float* __restrict__ bias,
                                               half_t* __restrict__ out) {
    extern __shared__ char smem[];
    half_t* Xs = (half_t*)smem;            // [64][128] swizzled
    half_t* Ws = (half_t*)(smem + 16384);  // [512][128] swizzled
    const int tid = threadIdx.x;
    const int bk = blockIdx.x;
    const int t = bk >> 2, b0 = (bk & 3) << 6;

    #pragma unroll
    for (int it = 0; it < 8; ++it) {
        int idx = tid + (it << 8);
        int r = idx >> 5, k = (idx & 31) << 2;
        float4 v = *(const float4*)(x + ((size_t)(b0 + r) * TSEQ + t) * DIN + k);
        half4v hv = {(half_t)v.x, (half_t)v.y, (half_t)v.z, (half_t)v.w};
        int byte = r * 256 + ((k * 2) ^ ((r & 7) << 4));
        *(half4v*)((char*)Xs + byte) = hv;
    }
    #pragma unroll 4
    for (int it = 0; it < 64; ++it) {
        int idx = tid + (it << 8);
        int r = idx >> 5, k = (idx & 31) << 2;
        float4 v = *(const float4*)(W + (size_t)r * DIN + k);
        half4v hv = {(half_t)v.x, (half_t)v.y, (half_t)v.z, (half_t)v.w};
        int byte = r * 256 + ((k * 2) ^ ((r & 7) << 4));
        *(half4v*)((char*)Ws + byte) = hv;
    }
    __syncthreads();

    const int lane = tid & 63, wv = tid >> 6;
    f32x4 acc[4][8];
    #pragma unroll
    for (int m = 0; m < 4; ++m)
        #pragma unroll
        for (int n = 0; n < 8; ++n) acc[m][n] = (f32x4){0.f, 0.f, 0.f, 0.f};

    #pragma unroll
    for (int kit = 0; kit < 4; ++kit) {
        int kk = (kit << 5) + ((lane >> 4) << 3);
        half8 a[4];
        #pragma unroll
        for (int m = 0; m < 4; ++m) {
            int r = (m << 4) + (lane & 15);
            int byte = r * 256 + ((kk * 2) ^ ((r & 7) << 4));
            a[m] = *(half8*)((char*)Xs + byte);
        }
        #pragma unroll
        for (int n = 0; n < 8; ++n) {
            int r = (wv << 7) + (n << 4) + (lane & 15);
            int byte = r * 256 + ((kk * 2) ^ ((r & 7) << 4));
            half8 b = *(half8*)((char*)Ws + byte);
            #pragma unroll
            for (int m = 0; m < 4; ++m)
                acc[m][n] = __builtin_amdgcn_mfma_f32_16x16x32_f16(a[m], b, acc[m][n], 0, 0, 0);
        }
    }
    __syncthreads();
    half_t* Os = (half_t*)smem;
    #pragma unroll
    for (int n = 0; n < 8; ++n) {
        int j = (wv << 7) + (n << 4) + (lane & 15);
        float bj = bias[j];
        #pragma unroll
        for (int m = 0; m < 4; ++m)
            #pragma unroll
            for (int r = 0; r < 4; ++r) {
                int mr = (m << 4) + ((lane >> 4) << 2) + r;
                Os[mr * 512 + j] = (half_t)(acc[m][n][r] + bj);
            }
    }
    __syncthreads();
    #pragma unroll
    for (int it = 0; it < 16; ++it) {
        int idx = tid + (it << 8);
        int r = idx >> 6, c = (idx & 63) << 3;
        half8 v = *(half8*)(Os + r * 512 + c);
        *(half8*)(out + ((size_t)t * NBAT + (b0 + r)) * HID + c) = v;
    }
}

// ---------------- persistent recurrent kernel (all 3 layers, 256 steps each)
__global__ __launch_bounds__(256, 1) void k_rec(const float* __restrict__ w_ih,
                                                const float* __restrict__ w_hh,
                                                const float* __restrict__ b_ih,
                                                const float* __restrict__ b_hh,
                                                half_t* __restrict__ bufA,
                                                half_t* __restrict__ bufB,
                                                int* __restrict__ flags) {
    extern __shared__ char smem[];
    float* Pl = (float*)smem;                 // [128][64] f32 partials (32KB), XOR-swz

    const int tid = threadIdx.x;
    const int lane = tid & 63, wv = tid >> 6;
    const int g = blockIdx.x & 7;             // batch group (static)
    const int hb = blockIdx.x >> 3;           // hidden part 0..31
    const int b0 = g << 5;
    const int j0 = hb << 4;
    int* myflag = flags + (g << 5) + hb;

    const int rr = tid >> 4;                  // reduce row 0..15
    const int jj = tid & 15;                  // reduce unit 0..15
    const bool hpart = (wv >= 2);
    const int kc = (wv & 1) << 8;             // K-chunk within source matrix
    const float* wsrc = hpart ? w_hh : w_ih;
    bool dead = false;

    float c0 = 0.f, c1 = 0.f;
    float bias[4];
    half8 Bf[8][4];                           // weight B-fragments (128 VGPR)
    half8 xa[8], xb[8];                       // X prefetch regs (X-waves)

    for (int l = 0; l < NL; ++l) {
        const half_t* inb = (l & 1) ? bufB : bufA;
        half_t* outb = (l & 1) ? bufA : bufB;
        // layer 2 re-reads bufA, whose lines were plain-cached during layer 0
        // with different values -> must use agent-scope X there.
        const bool xagent = (l == NL - 1);

        // ---- per-layer: weight fragments fp32 -> f16 into VGPRs
        #pragma unroll
        for (int kit = 0; kit < 8; ++kit)
            #pragma unroll
            for (int n = 0; n < 4; ++n) {
                int grow = l * 2048 + n * 512 + j0 + (lane & 15);
                int col = kc + (kit << 5) + ((lane >> 4) << 3);
                const float* p = wsrc + (size_t)grow * HID + col;
                float4 u0 = *(const float4*)p;
                float4 u1 = *(const float4*)(p + 4);
                Bf[kit][n] = (half8){(half_t)u0.x, (half_t)u0.y, (half_t)u0.z, (half_t)u0.w,
                                     (half_t)u1.x, (half_t)u1.y, (half_t)u1.z, (half_t)u1.w};
            }
        #pragma unroll
        for (int gt = 0; gt < 4; ++gt)
            bias[gt] = b_ih[(size_t)l * 2048 + gt * HID + j0 + jj] +
                       b_hh[(size_t)l * 2048 + gt * HID + j0 + jj];
        c0 = c1 = 0.f;

        for (int t = 0; t < TSEQ; ++t) {
            const int epoch = (l << 8) + t;
            f32x4 acc[2][4];
            #pragma unroll
            for (int m = 0; m < 2; ++m)
                #pragma unroll
                for (int n = 0; n < 4; ++n) acc[m][n] = (f32x4){0.f, 0.f, 0.f, 0.f};

            if (!hpart) {
                // X-waves: never wait on peers (X(t) is >=1 full layer old;
                // ordering transitively ensured by h-wave gate + barriers).
                if (t == 0) {
                    const half_t* ar = inb + ((size_t)b0 + (lane & 15)) * HID
                                       + kc + ((lane >> 4) << 3);
                    if (xagent) {
                        #pragma unroll
                        for (int kit = 0; kit < 8; ++kit) {
                            ld16_agent(xa[kit], ar + (kit << 5));
                            ld16_agent(xb[kit], ar + (size_t)16 * HID + (kit << 5));
                        }
                    } else {
                        #pragma unroll
                        for (int kit = 0; kit < 8; ++kit) {
                            xa[kit] = *(const half8*)(ar + (kit << 5));
                            xb[kit] = *(const half8*)(ar + (size_t)16 * HID + (kit << 5));
                        }
                    }
                }
                if (xagent) wait_vm0();  // prefetched regs landed (usually free)
                #pragma unroll
                for (int kit = 0; kit < 8; ++kit)
                    #pragma unroll
                    for (int n = 0; n < 4; ++n) {
                        acc[0][n] = __builtin_amdgcn_mfma_f32_16x16x32_f16(xa[kit], Bf[kit][n], acc[0][n], 0, 0, 0);
                        acc[1][n] = __builtin_amdgcn_mfma_f32_16x16x32_f16(xb[kit], Bf[kit][n], acc[1][n], 0, 0, 0);
                    }
                if (t + 1 < TSEQ) {  // prefetch X(t+1); hides under reduce+sync
                    const half_t* ar = inb + ((size_t)(t + 1) * NBAT + b0 + (lane & 15)) * HID
                                       + kc + ((lane >> 4) << 3);
                    if (xagent) {
                        #pragma unroll
                        for (int kit = 0; kit < 8; ++kit) {
                            ld16_agent(xa[kit], ar + (kit << 5));
                            ld16_agent(xb[kit], ar + (size_t)16 * HID + (kit << 5));
                        }
                    } else {
                        #pragma unroll
                        for (int kit = 0; kit < 8; ++kit) {
                            xa[kit] = *(const half8*)(ar + (kit << 5));
                            xb[kit] = *(const half8*)(ar + (size_t)16 * HID + (kit << 5));
                        }
                    }
                }
            } else {
                // h-waves: poll group flags (agent scope), then load h(t-1)
                if (!dead) {
                    const int* fp = flags + (g << 5) + (lane & 31);
                    bool ok = false;
                    int guard = 0;
                    while (!__all(ok)) {
                        if (!ok) ok = (__hip_atomic_load(fp, __ATOMIC_RELAXED,
                                                         __HIP_MEMORY_SCOPE_AGENT) >= epoch);
                        if (!ok) {
                            __builtin_amdgcn_s_sleep(1);
                            if (++guard > (1 << 17)) { dead = true; ok = true; }
                        }
                    }
                }
                if (t > 0) {
                    const half_t* hr = outb + ((size_t)(t - 1) * NBAT + b0 + (lane & 15)) * HID
                                       + kc + ((lane >> 4) << 3);
                    half8 ha[8], hc[8];
                    #pragma unroll
                    for (int kit = 0; kit < 8; ++kit) {
                        ld16_agent(ha[kit], hr + (kit << 5));
                        ld16_agent(hc[kit], hr + (size_t)16 * HID + (kit << 5));
                    }
                    wait_vm0();
                    #pragma unroll
                    for (int kit = 0; kit < 8; ++kit)
                        #pragma unroll
                        for (int n = 0; n < 4; ++n) {
                            acc[0][n] = __builtin_amdgcn_mfma_f32_16x16x32_f16(ha[kit], Bf[kit][n], acc[0][n], 0, 0, 0);
                            acc[1][n] = __builtin_amdgcn_mfma_f32_16x16x32_f16(hc[kit], Bf[kit][n], acc[1][n], 0, 0, 0);
                        }
                }
            }

            // ---- single-phase partials: all 4 waves' acc -> Pl (2-way swz = free)
            #pragma unroll
            for (int m = 0; m < 2; ++m)
                #pragma unroll
                for (int n = 0; n < 4; ++n)
                    #pragma unroll
                    for (int r = 0; r < 4; ++r) {
                        int prow = (wv << 5) + (m << 4) + ((lane >> 4) << 2) + r;
                        int cidx = (n << 4) + (lane & 15);
                        Pl[prow * 64 + (cidx ^ ((((prow >> 2) ^ prow) & 1) << 4))] = acc[m][n][r];
                    }
            __syncthreads();

            // ---- reduce + gates: thread (rr,jj) owns batch rows rr and rr+16
            float sv0[4], sv1[4];
            #pragma unroll
            for (int gt = 0; gt < 4; ++gt) {
                float s0 = bias[gt], s1 = bias[gt];
                int cidx = (gt << 4) + jj;
                #pragma unroll
                for (int w2 = 0; w2 < 4; ++w2) {
                    int r0 = (w2 << 5) + rr;
                    int r1 = (w2 << 5) + 16 + rr;
                    s0 += Pl[r0 * 64 + (cidx ^ ((((r0 >> 2) ^ r0) & 1) << 4))];
                    s1 += Pl[r1 * 64 + (cidx ^ ((((r1 >> 2) ^ r1) & 1) << 4))];
                }
                sv0[gt] = s0; sv1[gt] = s1;
            }
            {
                float ig = sigmoidf_(sv0[0]), fg = sigmoidf_(sv0[1]);
                float gg = tanhf_(sv0[2]), og = sigmoidf_(sv0[3]);
                c0 = fg * c0 + ig * gg;
                st_cg2(outb + ((size_t)t * NBAT + b0 + rr) * HID + j0 + jj, og * tanhf_(c0));
            }
            {
                float ig = sigmoidf_(sv1[0]), fg = sigmoidf_(sv1[1]);
                float gg = tanhf_(sv1[2]), og = sigmoidf_(sv1[3]);
                c1 = fg * c1 + ig * gg;
                st_cg2(outb + ((size_t)t * NBAT + b0 + 16 + rr) * HID + j0 + jj, og * tanhf_(c1));
            }

            // ---- release: drain h stores (agent-visible), barrier, publish
            asm volatile("s_waitcnt vmcnt(0)" ::: "memory");
            __builtin_amdgcn_sched_barrier(0);
            __syncthreads();
            if (tid == 0)
                __hip_atomic_store(myflag, epoch + 1, __ATOMIC_RELAXED,
                                   __HIP_MEMORY_SCOPE_AGENT);
        }
    }
}

// ---------------- decoder: out[b] = act[T-1][b][:] . dec_W + dec_b
__global__ __launch_bounds__(256) void k_dec(const half_t* __restrict__ act,
                                             const float* __restrict__ dW,
                                             const float* __restrict__ db,
                                             float* __restrict__ out) {
    int tid = threadIdx.x;
    int bl = tid >> 3, part = tid & 7;
    int b = (blockIdx.x << 5) + bl;
    const half_t* row = act + ((size_t)(TSEQ - 1) * NBAT + b) * HID + (part << 6);
    float s = 0.f;
    #pragma unroll
    for (int i = 0; i < 8; ++i) {
        half8 v = ld_cg16(row + (i << 3));
        const float* wp = dW + (part << 6) + (i << 3);
        #pragma unroll
        for (int u = 0; u < 8; ++u) s += (float)v[u] * wp[u];
    }
    #pragma unroll
    for (int off = 1; off < 8; off <<= 1) s += __shfl_xor(s, off, 64);
    if (part == 0) out[b] = s + db[0];
}

extern "C" void kernel_launch(void* const* d_in, const int* in_sizes, int n_in,
                              void* d_out, int out_size, void* d_ws, size_t ws_size,
                              hipStream_t stream) {
    const float* x = (const float*)d_in[0];
    const float* eW = (const float*)d_in[1];
    const float* eb = (const float*)d_in[2];
    const float* wih = (const float*)d_in[3];
    const float* whh = (const float*)d_in[4];
    const float* bih = (const float*)d_in[5];
    const float* bhh = (const float*)d_in[6];
    const float* dW = (const float*)d_in[7];
    const float* db = (const float*)d_in[8];
    float* out = (float*)d_out;

    const size_t BUF = (size_t)TSEQ * NBAT * HID * sizeof(half_t);  // 64 MB
    if (ws_size < 2 * BUF + 4096) return;  // insufficient workspace: fail loudly

    char* ws = (char*)d_ws;
    half_t* bufA = (half_t*)ws;
    half_t* bufB = (half_t*)(ws + BUF);
    int* flags = (int*)(ws + 2 * BUF);          // 256 ints

    hipMemsetAsync(flags, 0, 256 * sizeof(int), stream);

    (void)hipFuncSetAttribute((const void*)k_embed,
                              hipFuncAttributeMaxDynamicSharedMemorySize, 147456);
    (void)hipFuncSetAttribute((const void*)k_rec,
                              hipFuncAttributeMaxDynamicSharedMemorySize, 98304);

    k_embed<<<1024, 256, 147456, stream>>>(x, eW, eb, bufA);

    // 96KB dynamic LDS -> 1 block/CU; cooperative -> co-resident.
    void* args[] = { (void*)&wih, (void*)&whh, (void*)&bih, (void*)&bhh,
                     (void*)&bufA, (void*)&bufB, (void*)&flags };
    hipError_t ce = hipLaunchCooperativeKernel((const void*)k_rec, dim3(256), dim3(256),
                                               args, 98304, stream);
    if (ce != hipSuccess) {
        k_rec<<<256, 256, 98304, stream>>>(wih, whh, bih, bhh, bufA, bufB, flags);
    }

    k_dec<<<8, 256, 0, stream>>>(bufB, dW, db, out);
}